// Round 5
// baseline (127.959 us; speedup 1.0000x reference)
//
#include <hip/hip_runtime.h>

// Conv1dFFT via polyphase: y[b] = IFFT_8192( sum_p G_p * FFT_8192(x_polyphase_p) )
// Radix-8 register passes; same-wave passes chained without barriers (with
// compiler-only fences); two independent FFTs (j-pair) per barrier region in
// 128 KB static LDS. Accumulator mapped r = 8*tid+c so the first inverse
// radix-8 pass (unit twiddles) runs entirely in registers.

#define TK      8192
#define LOG2TK  13
#define HALF_TK 4096
#define KFOLD   8
#define NPAIR   4
#define TFULL   65536
#define NT      1024
#define RSQ2    0.70710678118654752440f

// LDS bank-conflict swizzle (bijective: low 4 bits XOR bits 4..7)
#define SW(i) ((i) ^ (((i) >> 4) & 15))

// Compiler-only ordering fence for wave-synchronous LDS hand-offs:
// prevents the scheduler from hoisting the next pass's ds_reads above the
// previous pass's ds_writes (other lanes' data). Emits no instructions.
#define WAVE_SYNC() do { asm volatile("" ::: "memory"); __builtin_amdgcn_wave_barrier(); } while (0)

__device__ __forceinline__ float2 cmul(float2 a, float2 b) {
    return make_float2(a.x * b.x - a.y * b.y, a.x * b.y + a.y * b.x);
}
__device__ __forceinline__ unsigned br13(unsigned r) { return __brev(r) >> 19u; }

__device__ float2 g_W[HALF_TK];        // e^{-2pi i t/8192}
__device__ float2 g_P[NPAIR * TK];     // bit-reversed order
__device__ float2 g_Q[NPAIR * TK];     // bit-reversed order

__global__ void build_twiddle_kernel() {
    int t = blockIdx.x * blockDim.x + threadIdx.x;
    if (t < HALF_TK) {
        double ang = -2.0 * 3.14159265358979323846 * (double)t / (double)TK;
        g_W[t] = make_float2((float)cos(ang), (float)sin(ang));
    }
}

__global__ void build_pq_kernel(const float* __restrict__ filt) {
    int t = blockIdx.x * blockDim.x + threadIdx.x;
    if (t >= TK) return;
    float fm[KFOLD];
#pragma unroll
    for (int m = 0; m < KFOLD; ++m) fm[m] = filt[m * TK + t];
    float2 G[KFOLD];
#pragma unroll
    for (int p = 0; p < KFOLD; ++p) {
        double sr = 0.0, si = 0.0;
#pragma unroll
        for (int m = 0; m < KFOLD; ++m) {
            double ang = -2.0 * 3.14159265358979323846 * (double)((p * m) & 7) / 8.0;
            sr += (double)fm[m] * cos(ang);
            si += (double)fm[m] * sin(ang);
        }
        double ang2 = -2.0 * 3.14159265358979323846 * (double)(p * t) / (double)TFULL;
        double c2 = cos(ang2), s2 = sin(ang2);
        G[p] = make_float2((float)((sr * c2 - si * s2) * 0.125),
                           (float)((sr * s2 + si * c2) * 0.125));
    }
    const float norm = 0.5f / (float)TK;
    unsigned r = br13((unsigned)t);
#pragma unroll
    for (int j = 0; j < NPAIR; ++j) {
        float2 g0 = G[2 * j], g1 = G[2 * j + 1];
        g_P[j * TK + r] = make_float2((g0.x + g1.y) * norm, (g0.y - g1.x) * norm);
        g_Q[j * TK + r] = make_float2((g0.x - g1.y) * norm, (g0.y + g1.x) * norm);
    }
}

// Forward DIF radix-8 pass: stages (4s, 2s, s), s = 1<<C.
template<int C>
__device__ __forceinline__ void fwd_pass(float2* buf, int tid) {
    const int s = 1 << C;
    const int q0 = tid & (s - 1);
    const int i0 = ((tid >> C) << (C + 3)) + q0;
    float2 e[8];
#pragma unroll
    for (int t = 0; t < 8; ++t) e[t] = buf[SW(i0 + t * s)];
    float2 w1, w2, w3;
    if (C == 0) { w1 = make_float2(1.f, 0.f); w2 = w1; w3 = w1; }
    else { w1 = g_W[q0 << (10 - C)]; w2 = cmul(w1, w1); w3 = cmul(w2, w2); }
    // stage h = 4s
#pragma unroll
    for (int t = 0; t < 4; ++t) {
        float2 a = e[t], b = e[t + 4];
        float2 d = make_float2(a.x - b.x, a.y - b.y);
        e[t] = make_float2(a.x + b.x, a.y + b.y);
        d = cmul(d, w1);
        if (t == 1)      d = make_float2(RSQ2 * (d.x + d.y), RSQ2 * (d.y - d.x));
        else if (t == 2) d = make_float2(d.y, -d.x);
        else if (t == 3) d = make_float2(RSQ2 * (d.y - d.x), -RSQ2 * (d.x + d.y));
        e[t + 4] = d;
    }
    // stage h = 2s
#pragma unroll
    for (int t0 = 0; t0 < 8; t0 += 4) {
#pragma unroll
        for (int t = 0; t < 2; ++t) {
            int i = t0 + t;
            float2 a = e[i], b = e[i + 2];
            float2 d = make_float2(a.x - b.x, a.y - b.y);
            e[i] = make_float2(a.x + b.x, a.y + b.y);
            d = cmul(d, w2);
            if (t == 1) d = make_float2(d.y, -d.x);
            e[i + 2] = d;
        }
    }
    // stage h = s
#pragma unroll
    for (int t = 0; t < 8; t += 2) {
        float2 a = e[t], b = e[t + 1];
        float2 d = make_float2(a.x - b.x, a.y - b.y);
        e[t] = make_float2(a.x + b.x, a.y + b.y);
        e[t + 1] = cmul(d, w3);
    }
#pragma unroll
    for (int t = 0; t < 8; ++t) buf[SW(i0 + t * s)] = e[t];
}

// Inverse DIT radix-8 pass: stages (s, 2s, 4s), conjugated twiddles.
template<int C>
__device__ __forceinline__ void inv_pass(float2* buf, int tid) {
    const int s = 1 << C;
    const int q0 = tid & (s - 1);
    const int i0 = ((tid >> C) << (C + 3)) + q0;
    float2 e[8];
#pragma unroll
    for (int t = 0; t < 8; ++t) e[t] = buf[SW(i0 + t * s)];
    float2 v1, v2, v3;
    if (C == 0) { v1 = make_float2(1.f, 0.f); v2 = v1; v3 = v1; }
    else { v1 = g_W[q0 << (10 - C)]; v1.y = -v1.y; v2 = cmul(v1, v1); v3 = cmul(v2, v2); }
    // stage h = s
#pragma unroll
    for (int t = 0; t < 8; t += 2) {
        float2 b = cmul(e[t + 1], v3);
        float2 a = e[t];
        e[t]     = make_float2(a.x + b.x, a.y + b.y);
        e[t + 1] = make_float2(a.x - b.x, a.y - b.y);
    }
    // stage h = 2s
#pragma unroll
    for (int t0 = 0; t0 < 8; t0 += 4) {
#pragma unroll
        for (int t = 0; t < 2; ++t) {
            int i = t0 + t;
            float2 b = cmul(e[i + 2], v2);
            if (t == 1) b = make_float2(-b.y, b.x);
            float2 a = e[i];
            e[i]     = make_float2(a.x + b.x, a.y + b.y);
            e[i + 2] = make_float2(a.x - b.x, a.y - b.y);
        }
    }
    // stage h = 4s
#pragma unroll
    for (int t = 0; t < 4; ++t) {
        float2 b = cmul(e[t + 4], v1);
        if (t == 1)      b = make_float2(RSQ2 * (b.x - b.y), RSQ2 * (b.x + b.y));
        else if (t == 2) b = make_float2(-b.y, b.x);
        else if (t == 3) b = make_float2(-RSQ2 * (b.x + b.y), RSQ2 * (b.x - b.y));
        float2 a = e[t];
        e[t]     = make_float2(a.x + b.x, a.y + b.y);
        e[t + 4] = make_float2(a.x - b.x, a.y - b.y);
    }
#pragma unroll
    for (int t = 0; t < 8; ++t) buf[SW(i0 + t * s)] = e[t];
}

__global__ __launch_bounds__(NT)
void conv_fft_kernel(const float* __restrict__ x, float2* __restrict__ out) {
    __shared__ float2 smem[2 * TK];           // 128 KB static: two 8192-pt buffers
    float2* bufA = smem;
    float2* bufB = smem + TK;
    const int tid = threadIdx.x;
    const int b = blockIdx.x;
    const float4* __restrict__ xrow4 =
        reinterpret_cast<const float4*>(x + (size_t)b * TFULL);

    float2 acc[8];
#pragma unroll
    for (int c = 0; c < 8; ++c) acc[c] = make_float2(0.f, 0.f);

    for (int jp = 0; jp < 2; ++jp) {          // FFT pair: j = 2jp (A), 2jp+1 (B)
        // global float4 load fused with first DIF stage (h = 4096), both buffers
#pragma unroll
        for (int c4 = 0; c4 < 4; ++c4) {
            int u = c4 * NT + tid;
            float4 a  = xrow4[2 * u + jp];                 // (reA,imA,reB,imB) @ u
            float4 b2 = xrow4[2 * (u + HALF_TK) + jp];     // @ u+4096
            float2 w = g_W[u];
            bufA[SW(u)] = make_float2(a.x + b2.x, a.y + b2.y);
            bufA[SW(u + HALF_TK)] = cmul(make_float2(a.x - b2.x, a.y - b2.y), w);
            bufB[SW(u)] = make_float2(a.z + b2.z, a.w + b2.w);
            bufB[SW(u + HALF_TK)] = cmul(make_float2(a.z - b2.z, a.w - b2.w), w);
        }
        __syncthreads();
        fwd_pass<9>(bufA, tid); fwd_pass<9>(bufB, tid);
        __syncthreads();
        // C6 -> C3 -> C0 communicate only within a wave: compiler fence only
        fwd_pass<6>(bufA, tid); fwd_pass<6>(bufB, tid);
        WAVE_SYNC();
        fwd_pass<3>(bufA, tid); fwd_pass<3>(bufB, tid);
        WAVE_SYNC();
        fwd_pass<0>(bufA, tid); fwd_pass<0>(bufB, tid);
        __syncthreads();
        // accumulate at r = 8*tid + c: y_hat += Z*P + conj(Z[-t])*Q
        const float2* __restrict__ PA = g_P + (size_t)(2 * jp) * TK;
        const float2* __restrict__ QA = g_Q + (size_t)(2 * jp) * TK;
        const float2* __restrict__ PB = g_P + (size_t)(2 * jp + 1) * TK;
        const float2* __restrict__ QB = g_Q + (size_t)(2 * jp + 1) * TK;
#pragma unroll
        for (int c = 0; c < 8; ++c) {
            int r = 8 * tid + c;
            unsigned t = br13((unsigned)r);
            unsigned tm = (TK - t) & (TK - 1);
            int r2 = (int)br13(tm);
            float2 ZtA = bufA[SW(r)], ZmA = bufA[SW(r2)];
            float2 ZtB = bufB[SW(r)], ZmB = bufB[SW(r2)];
            float2 Pa = PA[r], Qa = QA[r], Pb = PB[r], Qb = QB[r];
            acc[c].x += ZtA.x * Pa.x - ZtA.y * Pa.y + ZmA.x * Qa.x + ZmA.y * Qa.y
                      + ZtB.x * Pb.x - ZtB.y * Pb.y + ZmB.x * Qb.x + ZmB.y * Qb.y;
            acc[c].y += ZtA.x * Pa.y + ZtA.y * Pa.x + ZmA.x * Qa.y - ZmA.y * Qa.x
                      + ZtB.x * Pb.y + ZtB.y * Pb.x + ZmB.x * Qb.y - ZmB.y * Qb.x;
        }
        __syncthreads();
    }

    // First inverse radix-8 pass (C=0, unit twiddles) in registers:
    // thread tid owns y_hat_br[8*tid .. 8*tid+8) == acc[0..8)
    {
        float2 e[8];
        // stage h = 1
#pragma unroll
        for (int t = 0; t < 8; t += 2) {
            float2 a = acc[t], bb = acc[t + 1];
            e[t]     = make_float2(a.x + bb.x, a.y + bb.y);
            e[t + 1] = make_float2(a.x - bb.x, a.y - bb.y);
        }
        // stage h = 2 (twiddle (+i)^(t&1))
#pragma unroll
        for (int t0 = 0; t0 < 8; t0 += 4) {
            {
                float2 a = e[t0], bb = e[t0 + 2];
                e[t0]     = make_float2(a.x + bb.x, a.y + bb.y);
                e[t0 + 2] = make_float2(a.x - bb.x, a.y - bb.y);
            }
            {
                float2 a = e[t0 + 1], bb = e[t0 + 3];
                bb = make_float2(-bb.y, bb.x);
                e[t0 + 1] = make_float2(a.x + bb.x, a.y + bb.y);
                e[t0 + 3] = make_float2(a.x - bb.x, a.y - bb.y);
            }
        }
        // stage h = 4 (twiddle conj(u8)^t)
#pragma unroll
        for (int t = 0; t < 4; ++t) {
            float2 bb = e[t + 4];
            if (t == 1)      bb = make_float2(RSQ2 * (bb.x - bb.y), RSQ2 * (bb.x + bb.y));
            else if (t == 2) bb = make_float2(-bb.y, bb.x);
            else if (t == 3) bb = make_float2(-RSQ2 * (bb.x + bb.y), RSQ2 * (bb.x - bb.y));
            float2 a = e[t];
            e[t]     = make_float2(a.x + bb.x, a.y + bb.y);
            e[t + 4] = make_float2(a.x - bb.x, a.y - bb.y);
        }
#pragma unroll
        for (int t = 0; t < 8; ++t) bufA[SW(8 * tid + t)] = e[t];
    }
    WAVE_SYNC();
    // C0 -> C3 -> C6 same-wave; barrier before the cross-wave C9
    inv_pass<3>(bufA, tid);
    WAVE_SYNC();
    inv_pass<6>(bufA, tid);
    __syncthreads();
    inv_pass<9>(bufA, tid);
    __syncthreads();
    // final DIT stage (h = 4096) fused with global store
    float2* __restrict__ orow = out + (size_t)b * TK;
#pragma unroll
    for (int c4 = 0; c4 < 4; ++c4) {
        int u = c4 * NT + tid;
        float2 a = bufA[SW(u)];
        float2 w = g_W[u]; w.y = -w.y;
        float2 bb = cmul(bufA[SW(u + HALF_TK)], w);
        orow[u]           = make_float2(a.x + bb.x, a.y + bb.y);
        orow[u + HALF_TK] = make_float2(a.x - bb.x, a.y - bb.y);
    }
}

extern "C" void kernel_launch(void* const* d_in, const int* in_sizes, int n_in,
                              void* d_out, int out_size, void* d_ws, size_t ws_size,
                              hipStream_t stream) {
    const float* x    = (const float*)d_in[0];
    const float* filt = (const float*)d_in[1];
    const int T = in_sizes[1];          // 65536
    const int B = in_sizes[0] / T;      // 256 rows
    (void)n_in; (void)d_ws; (void)ws_size; (void)out_size; (void)T;

    build_twiddle_kernel<<<HALF_TK / 256, 256, 0, stream>>>();
    build_pq_kernel<<<TK / 256, 256, 0, stream>>>(filt);
    conv_fft_kernel<<<B, NT, 0, stream>>>(x, (float2*)d_out);
}

// Round 6
// 125.274 us; speedup vs baseline: 1.0214x; 1.0214x over previous
//
#include <hip/hip_runtime.h>

// Conv1dFFT via polyphase: y[b] = IFFT_8192( sum_p G_p * FFT_8192(x_polyphase_p) )
// Round-2 proven structure (sequential j, 64 KB LDS, full barriers) +
// load-once/register-stash x reads + register inverse-C0 tail.

#define TK      8192
#define LOG2TK  13
#define HALF_TK 4096
#define KFOLD   8
#define NPAIR   4
#define TFULL   65536
#define NT      1024
#define RSQ2    0.70710678118654752440f

// LDS bank-conflict swizzle (bijective: low 4 bits XOR bits 4..7)
#define SW(i) ((i) ^ (((i) >> 4) & 15))

__device__ __forceinline__ float2 cmul(float2 a, float2 b) {
    return make_float2(a.x * b.x - a.y * b.y, a.x * b.y + a.y * b.x);
}
__device__ __forceinline__ unsigned br13(unsigned r) { return __brev(r) >> 19u; }

__device__ float2 g_W[HALF_TK];        // e^{-2pi i t/8192}
__device__ float2 g_P[NPAIR * TK];     // bit-reversed order
__device__ float2 g_Q[NPAIR * TK];     // bit-reversed order

__global__ void build_twiddle_kernel() {
    int t = blockIdx.x * blockDim.x + threadIdx.x;
    if (t < HALF_TK) {
        double ang = -2.0 * 3.14159265358979323846 * (double)t / (double)TK;
        g_W[t] = make_float2((float)cos(ang), (float)sin(ang));
    }
}

__global__ void build_pq_kernel(const float* __restrict__ filt) {
    int t = blockIdx.x * blockDim.x + threadIdx.x;
    if (t >= TK) return;
    float fm[KFOLD];
#pragma unroll
    for (int m = 0; m < KFOLD; ++m) fm[m] = filt[m * TK + t];
    float2 G[KFOLD];
#pragma unroll
    for (int p = 0; p < KFOLD; ++p) {
        double sr = 0.0, si = 0.0;
#pragma unroll
        for (int m = 0; m < KFOLD; ++m) {
            double ang = -2.0 * 3.14159265358979323846 * (double)((p * m) & 7) / 8.0;
            sr += (double)fm[m] * cos(ang);
            si += (double)fm[m] * sin(ang);
        }
        double ang2 = -2.0 * 3.14159265358979323846 * (double)(p * t) / (double)TFULL;
        double c2 = cos(ang2), s2 = sin(ang2);
        G[p] = make_float2((float)((sr * c2 - si * s2) * 0.125),
                           (float)((sr * s2 + si * c2) * 0.125));
    }
    const float norm = 0.5f / (float)TK;
    unsigned r = br13((unsigned)t);
#pragma unroll
    for (int j = 0; j < NPAIR; ++j) {
        float2 g0 = G[2 * j], g1 = G[2 * j + 1];
        g_P[j * TK + r] = make_float2((g0.x + g1.y) * norm, (g0.y - g1.x) * norm);
        g_Q[j * TK + r] = make_float2((g0.x - g1.y) * norm, (g0.y + g1.x) * norm);
    }
}

// Forward DIF radix-8 pass: stages (4s, 2s, s), s = 1<<C.
template<int C>
__device__ __forceinline__ void fwd_pass(float2* buf, int tid) {
    const int s = 1 << C;
    const int q0 = tid & (s - 1);
    const int i0 = ((tid >> C) << (C + 3)) + q0;
    float2 e[8];
#pragma unroll
    for (int t = 0; t < 8; ++t) e[t] = buf[SW(i0 + t * s)];
    float2 w1, w2, w3;
    if (C == 0) { w1 = make_float2(1.f, 0.f); w2 = w1; w3 = w1; }
    else { w1 = g_W[q0 << (10 - C)]; w2 = cmul(w1, w1); w3 = cmul(w2, w2); }
    // stage h = 4s
#pragma unroll
    for (int t = 0; t < 4; ++t) {
        float2 a = e[t], b = e[t + 4];
        float2 d = make_float2(a.x - b.x, a.y - b.y);
        e[t] = make_float2(a.x + b.x, a.y + b.y);
        d = cmul(d, w1);
        if (t == 1)      d = make_float2(RSQ2 * (d.x + d.y), RSQ2 * (d.y - d.x));
        else if (t == 2) d = make_float2(d.y, -d.x);
        else if (t == 3) d = make_float2(RSQ2 * (d.y - d.x), -RSQ2 * (d.x + d.y));
        e[t + 4] = d;
    }
    // stage h = 2s
#pragma unroll
    for (int t0 = 0; t0 < 8; t0 += 4) {
#pragma unroll
        for (int t = 0; t < 2; ++t) {
            int i = t0 + t;
            float2 a = e[i], b = e[i + 2];
            float2 d = make_float2(a.x - b.x, a.y - b.y);
            e[i] = make_float2(a.x + b.x, a.y + b.y);
            d = cmul(d, w2);
            if (t == 1) d = make_float2(d.y, -d.x);
            e[i + 2] = d;
        }
    }
    // stage h = s
#pragma unroll
    for (int t = 0; t < 8; t += 2) {
        float2 a = e[t], b = e[t + 1];
        float2 d = make_float2(a.x - b.x, a.y - b.y);
        e[t] = make_float2(a.x + b.x, a.y + b.y);
        e[t + 1] = cmul(d, w3);
    }
#pragma unroll
    for (int t = 0; t < 8; ++t) buf[SW(i0 + t * s)] = e[t];
}

// Inverse DIT radix-8 pass: stages (s, 2s, 4s), conjugated twiddles.
template<int C>
__device__ __forceinline__ void inv_pass(float2* buf, int tid) {
    const int s = 1 << C;
    const int q0 = tid & (s - 1);
    const int i0 = ((tid >> C) << (C + 3)) + q0;
    float2 e[8];
#pragma unroll
    for (int t = 0; t < 8; ++t) e[t] = buf[SW(i0 + t * s)];
    float2 v1, v2, v3;
    if (C == 0) { v1 = make_float2(1.f, 0.f); v2 = v1; v3 = v1; }
    else { v1 = g_W[q0 << (10 - C)]; v1.y = -v1.y; v2 = cmul(v1, v1); v3 = cmul(v2, v2); }
    // stage h = s
#pragma unroll
    for (int t = 0; t < 8; t += 2) {
        float2 b = cmul(e[t + 1], v3);
        float2 a = e[t];
        e[t]     = make_float2(a.x + b.x, a.y + b.y);
        e[t + 1] = make_float2(a.x - b.x, a.y - b.y);
    }
    // stage h = 2s
#pragma unroll
    for (int t0 = 0; t0 < 8; t0 += 4) {
#pragma unroll
        for (int t = 0; t < 2; ++t) {
            int i = t0 + t;
            float2 b = cmul(e[i + 2], v2);
            if (t == 1) b = make_float2(-b.y, b.x);
            float2 a = e[i];
            e[i]     = make_float2(a.x + b.x, a.y + b.y);
            e[i + 2] = make_float2(a.x - b.x, a.y - b.y);
        }
    }
    // stage h = 4s
#pragma unroll
    for (int t = 0; t < 4; ++t) {
        float2 b = cmul(e[t + 4], v1);
        if (t == 1)      b = make_float2(RSQ2 * (b.x - b.y), RSQ2 * (b.x + b.y));
        else if (t == 2) b = make_float2(-b.y, b.x);
        else if (t == 3) b = make_float2(-RSQ2 * (b.x + b.y), RSQ2 * (b.x - b.y));
        float2 a = e[t];
        e[t]     = make_float2(a.x + b.x, a.y + b.y);
        e[t + 4] = make_float2(a.x - b.x, a.y - b.y);
    }
#pragma unroll
    for (int t = 0; t < 8; ++t) buf[SW(i0 + t * s)] = e[t];
}

__device__ __forceinline__ void stage1_store(float2* buf, int u, float2 a, float2 b2) {
    float2 w = g_W[u];
    buf[SW(u)] = make_float2(a.x + b2.x, a.y + b2.y);
    buf[SW(u + HALF_TK)] = cmul(make_float2(a.x - b2.x, a.y - b2.y), w);
}

// barrier; 4 radix-8 passes (barrier-separated, round-2 proven); accumulate; barrier
__device__ __forceinline__ void fft_body_and_acc(float2* buf, int tid,
                                                 const float2* __restrict__ P,
                                                 const float2* __restrict__ Q,
                                                 float2* acc) {
    __syncthreads();
    fwd_pass<9>(buf, tid);
    __syncthreads();
    fwd_pass<6>(buf, tid);
    __syncthreads();
    fwd_pass<3>(buf, tid);
    __syncthreads();
    fwd_pass<0>(buf, tid);
    __syncthreads();
#pragma unroll
    for (int c = 0; c < 8; ++c) {
        int r = 8 * tid + c;
        unsigned t = br13((unsigned)r);
        unsigned tm = (TK - t) & (TK - 1);
        int r2 = (int)br13(tm);
        float2 Zt = buf[SW(r)];
        float2 Zm = buf[SW(r2)];
        float2 Pv = P[r], Qv = Q[r];
        acc[c].x += Zt.x * Pv.x - Zt.y * Pv.y + Zm.x * Qv.x + Zm.y * Qv.y;
        acc[c].y += Zt.x * Pv.y + Zt.y * Pv.x + Zm.x * Qv.y - Zm.y * Qv.x;
    }
    __syncthreads();
}

__global__ __launch_bounds__(NT, 4)
void conv_fft_kernel(const float* __restrict__ x, float2* __restrict__ out) {
    __shared__ float2 buf[TK];   // 64 KB
    const int tid = threadIdx.x;
    const int b = blockIdx.x;
    const float4* __restrict__ xrow4 =
        reinterpret_cast<const float4*>(x + (size_t)b * TFULL);

    float2 acc[8];
#pragma unroll
    for (int c = 0; c < 8; ++c) acc[c] = make_float2(0.f, 0.f);

    // ---- j = 0: load xrow4[2u] (even float4s), use .xy, stash .zw for j=1 ----
    float2 s1a[4], s1b[4];
    {
        float4 f0a[4], f0b[4];
#pragma unroll
        for (int c4 = 0; c4 < 4; ++c4) {
            int u = c4 * NT + tid;
            f0a[c4] = xrow4[2 * u];
            f0b[c4] = xrow4[2 * (u + HALF_TK)];
        }
#pragma unroll
        for (int c4 = 0; c4 < 4; ++c4) {
            int u = c4 * NT + tid;
            s1a[c4] = make_float2(f0a[c4].z, f0a[c4].w);
            s1b[c4] = make_float2(f0b[c4].z, f0b[c4].w);
            stage1_store(buf, u, make_float2(f0a[c4].x, f0a[c4].y),
                                  make_float2(f0b[c4].x, f0b[c4].y));
        }
    }
    fft_body_and_acc(buf, tid, g_P + 0 * TK, g_Q + 0 * TK, acc);

    // ---- j = 1: prefetch odd float4s (for j=2/3); stage-1 from register stash ----
    float4 f1a[4], f1b[4];
#pragma unroll
    for (int c4 = 0; c4 < 4; ++c4) {
        int u = c4 * NT + tid;
        f1a[c4] = xrow4[2 * u + 1];
        f1b[c4] = xrow4[2 * (u + HALF_TK) + 1];
    }
#pragma unroll
    for (int c4 = 0; c4 < 4; ++c4) {
        int u = c4 * NT + tid;
        stage1_store(buf, u, s1a[c4], s1b[c4]);
    }
    fft_body_and_acc(buf, tid, g_P + 1 * TK, g_Q + 1 * TK, acc);

    // ---- j = 2: stage-1 from f1 .xy; stash .zw for j=3 ----
    float2 s3a[4], s3b[4];
#pragma unroll
    for (int c4 = 0; c4 < 4; ++c4) {
        int u = c4 * NT + tid;
        s3a[c4] = make_float2(f1a[c4].z, f1a[c4].w);
        s3b[c4] = make_float2(f1b[c4].z, f1b[c4].w);
        stage1_store(buf, u, make_float2(f1a[c4].x, f1a[c4].y),
                              make_float2(f1b[c4].x, f1b[c4].y));
    }
    fft_body_and_acc(buf, tid, g_P + 2 * TK, g_Q + 2 * TK, acc);

    // ---- j = 3: stage-1 from register stash ----
#pragma unroll
    for (int c4 = 0; c4 < 4; ++c4) {
        int u = c4 * NT + tid;
        stage1_store(buf, u, s3a[c4], s3b[c4]);
    }
    fft_body_and_acc(buf, tid, g_P + 3 * TK, g_Q + 3 * TK, acc);

    // ---- inverse FFT tail ----
    // First inverse radix-8 pass (C=0, unit twiddles) in registers:
    // thread tid owns y_hat_br[8*tid .. 8*tid+8) == acc[0..8)  (proven in R5)
    {
        float2 e[8];
        // stage h = 1
#pragma unroll
        for (int t = 0; t < 8; t += 2) {
            float2 a = acc[t], bb = acc[t + 1];
            e[t]     = make_float2(a.x + bb.x, a.y + bb.y);
            e[t + 1] = make_float2(a.x - bb.x, a.y - bb.y);
        }
        // stage h = 2 (twiddle (+i)^(t&1))
#pragma unroll
        for (int t0 = 0; t0 < 8; t0 += 4) {
            {
                float2 a = e[t0], bb = e[t0 + 2];
                e[t0]     = make_float2(a.x + bb.x, a.y + bb.y);
                e[t0 + 2] = make_float2(a.x - bb.x, a.y - bb.y);
            }
            {
                float2 a = e[t0 + 1], bb = e[t0 + 3];
                bb = make_float2(-bb.y, bb.x);
                e[t0 + 1] = make_float2(a.x + bb.x, a.y + bb.y);
                e[t0 + 3] = make_float2(a.x - bb.x, a.y - bb.y);
            }
        }
        // stage h = 4 (twiddle conj(u8)^t)
#pragma unroll
        for (int t = 0; t < 4; ++t) {
            float2 bb = e[t + 4];
            if (t == 1)      bb = make_float2(RSQ2 * (bb.x - bb.y), RSQ2 * (bb.x + bb.y));
            else if (t == 2) bb = make_float2(-bb.y, bb.x);
            else if (t == 3) bb = make_float2(-RSQ2 * (bb.x + bb.y), RSQ2 * (bb.x - bb.y));
            float2 a = e[t];
            e[t]     = make_float2(a.x + bb.x, a.y + bb.y);
            e[t + 4] = make_float2(a.x - bb.x, a.y - bb.y);
        }
#pragma unroll
        for (int t = 0; t < 8; ++t) buf[SW(8 * tid + t)] = e[t];
    }
    __syncthreads();
    inv_pass<3>(buf, tid);
    __syncthreads();
    inv_pass<6>(buf, tid);
    __syncthreads();
    inv_pass<9>(buf, tid);
    __syncthreads();
    // final DIT stage (h = 4096) fused with global store
    float2* __restrict__ orow = out + (size_t)b * TK;
#pragma unroll
    for (int c4 = 0; c4 < 4; ++c4) {
        int u = c4 * NT + tid;
        float2 a = buf[SW(u)];
        float2 w = g_W[u]; w.y = -w.y;
        float2 bb = cmul(buf[SW(u + HALF_TK)], w);
        orow[u]           = make_float2(a.x + bb.x, a.y + bb.y);
        orow[u + HALF_TK] = make_float2(a.x - bb.x, a.y - bb.y);
    }
}

extern "C" void kernel_launch(void* const* d_in, const int* in_sizes, int n_in,
                              void* d_out, int out_size, void* d_ws, size_t ws_size,
                              hipStream_t stream) {
    const float* x    = (const float*)d_in[0];
    const float* filt = (const float*)d_in[1];
    const int T = in_sizes[1];          // 65536
    const int B = in_sizes[0] / T;      // 256 rows
    (void)n_in; (void)d_ws; (void)ws_size; (void)out_size; (void)T;

    build_twiddle_kernel<<<HALF_TK / 256, 256, 0, stream>>>();
    build_pq_kernel<<<TK / 256, 256, 0, stream>>>(filt);
    conv_fft_kernel<<<B, NT, 0, stream>>>(x, (float2*)d_out);
}